// Round 6
// baseline (394.940 us; speedup 1.0000x reference)
//
#include <hip/hip_runtime.h>

// ASIC_87007447483060 — soft logic-rail update, fused single pass.
// R2: 227us total. R3 (float4 tg): neutral. R5 (occupancy/nontemporal/fused
//     boundary): neutral. All variants 225-230us.
// Deduction: dur_us includes harness restore/poison (>=146us); our kernel is
//     somewhere in [27,79]us — unresolvable from top-5 counters (all fills).
// R6: MEASUREMENT ROUND. Launch the identical idempotent kernel 5x; the 4
//     extra replicas expose T_kernel = (dur_us - 225)/4.
//     Floor hypothesis -> dur ~305-365; pathology hypothesis -> dur ~505-605.

constexpr int N     = 1024;
constexpr int NP1   = N + 1;           // 1025
constexpr int PLANE = NP1 * NP1;       // 1050625
constexpr int NN    = N * N;

typedef float floatx4 __attribute__((ext_vector_type(4)));

__device__ __forceinline__ float sigmoidf_fast(float t) {
    return __builtin_amdgcn_rcpf(1.0f + __expf(-t));
}

// 1024 blocks x 256 threads. Each thread owns 4 consecutive interior pixels
// (r, c0..c0+3), c0 % 4 == 0. Threads tid < 8196 additionally handle one
// boundary passthrough cell (disjoint from all main scatter targets).
// Main scatter: planes 0,1 -> (r,c); planes 2,3 -> (r+1,c+1).
__global__ __launch_bounds__(256, 5) void asic_fused(
    const float* __restrict__ x,
    const float* __restrict__ tg,
    const float* __restrict__ rail,
    const int*  __restrict__ mask,
    float* __restrict__ out)
{
    const int tid  = blockIdx.x * 256 + threadIdx.x;   // 262144 threads
    const float g0 = tg[0];

    // ---- boundary passthrough (2n+1 cells per plane, 8196 total) ----
    {
        const int per = 2 * N + 1;  // 2049
        if (tid < 4 * per) {
            const int plane = tid / per;
            const int k = tid % per;
            int r, c;
            if (plane < 2) {                    // row n + col n (rows 0..n-1)
                if (k <= N) { r = N; c = k; }
                else        { r = k - (N + 1); c = N; }
            } else {                            // row 0 + col 0 (rows 1..n)
                if (k <= N) { r = 0; c = k; }
                else        { r = k - N; c = 0; }
            }
            const int flat = plane * PLANE + r * NP1 + c;
            float v = (plane == 3 && c == 0 && r < N) ? x[r] : rail[flat];
            out[flat] = v * (float)mask[flat] * g0;
        }
    }

    // ---- main: 4 pixels per thread ----
    const int pix0 = tid << 2;
    const int r    = pix0 >> 10;
    const int c0   = pix0 & (N - 1);

    // Gather new_inputs (persistent: 16 VGPRs).
    float u[4][4];
    const int b01 = (r + 1) * NP1 + (c0 + 1);
    const int b23 = r * NP1 + c0;
#pragma unroll
    for (int q = 0; q < 4; ++q) {
        u[0][q] = rail[0 * PLANE + b01 + q];
        u[1][q] = rail[1 * PLANE + b01 + q];
        u[2][q] = rail[2 * PLANE + b23 + q];
        u[3][q] = rail[3 * PLANE + b23 + q];
    }
    if (c0 == 0) u[3][0] = x[r];   // view-write of x into plane 3, col 0

#pragma unroll
    for (int i = 0; i < 4; ++i) {
        const int o0 = (i == 0) ? 1 : 0;     // others[i], ascending
        const int o1 = (i <= 1) ? 2 : 1;
        const int o2 = (i <= 2) ? 3 : 2;

        // Soft-AND factors for this phase only (recomputed -> fewer live regs).
        float A0[4], A1[4], B0[4], B1[4], C0[4], C1[4];
#pragma unroll
        for (int q = 0; q < 4; ++q) {
            A0[q] = 1.0f - fabsf(u[o0][q]);  A1[q] = 1.0f - fabsf(1.0f - u[o0][q]);
            B0[q] = 1.0f - fabsf(u[o1][q]);  B1[q] = 1.0f - fabsf(1.0f - u[o1][q]);
            C0[q] = 1.0f - fabsf(u[o2][q]);  C1[q] = 1.0f - fabsf(1.0f - u[o2][q]);
        }

        float s0[4] = {0.f, 0.f, 0.f, 0.f};   // sum_p w_p
        float s1[4] = {0.f, 0.f, 0.f, 0.f};   // sum_p tw_p * w_p
#pragma unroll
        for (int p = 0; p < 8; ++p) {
            // Streaming (nontemporal) aligned 16B load of 4 gate values.
            const floatx4 tv = __builtin_nontemporal_load(
                reinterpret_cast<const floatx4*>(&tg[(i * 8 + p) * NN + pix0]));
            const float tw[4] = { sigmoidf_fast(tv.x), sigmoidf_fast(tv.y),
                                  sigmoidf_fast(tv.z), sigmoidf_fast(tv.w) };
            const int b0 = p >> 2, b1 = (p >> 1) & 1, b2 = p & 1;
#pragma unroll
            for (int q = 0; q < 4; ++q) {
                const float w = (b0 ? A1[q] : A0[q]) *
                                (b1 ? B1[q] : B0[q]) *
                                (b2 ? C1[q] : C0[q]);
                s0[q] += w;
                s1[q]  = fmaf(tw[q], w, s1[q]);
            }
        }

        // sum_p toggled_p w_p = (2u-1) s1 + (1-u) s0, clip, mask, scale.
#pragma unroll
        for (int q = 0; q < 4; ++q) {
            const float A = 2.0f * u[i][q] - 1.0f;
            const float B = 1.0f - u[i][q];
            float acc = fmaf(A, s1[q], B * s0[q]);
            acc = fminf(fmaxf(acc, 0.0f), 1.0f);
            const int flat = (i < 2) ? (i * PLANE + r * NP1 + (c0 + q))
                                     : (i * PLANE + (r + 1) * NP1 + (c0 + q + 1));
            __builtin_nontemporal_store(acc * (float)mask[flat] * g0, &out[flat]);
        }
    }
}

extern "C" void kernel_launch(void* const* d_in, const int* in_sizes, int n_in,
                              void* d_out, int out_size, void* d_ws, size_t ws_size,
                              hipStream_t stream) {
    const float* x    = (const float*)d_in[0];   // (n,)
    const float* tg   = (const float*)d_in[1];   // (4,8,n,n)
    const float* rail = (const float*)d_in[2];   // (4*(n+1)^2,)
    const int*   mask = (const int*)d_in[3];     // (4*(n+1)^2,)
    float* out = (float*)d_out;                  // (4*(n+1)^2,) f32

    // MEASUREMENT: 5 identical idempotent launches. T_kernel = (dur-225)/4.
    // (Same work every call; reads only d_in, writes only d_out.)
    for (int rep = 0; rep < 5; ++rep) {
        asic_fused<<<(NN / 4) / 256, 256, 0, stream>>>(x, tg, rail, mask, out);
    }
}

// Round 8
// 220.166 us; speedup vs baseline: 1.7938x; 1.7938x over previous
//
#include <hip/hip_runtime.h>

// ASIC_87007447483060 — soft logic-rail update, fused single pass.
// R6 measurement: T_kernel = 42.4us (5x-replica delta) vs 29us floor on the
//     irreducible 185 MB; harness fixed share ~183us of dur_us.
// R7/R8: (1) plain stores (L2 write-combining for the c0+1-misaligned scatter;
//     nt stores bypass L2 -> partial-line HBM writes), (2) exact
//     factorization s0 = prod(F0+F1), s1 via nested 3-level contraction
//     (14 ops vs 32 per phase*pixel, frees ~24 VGPRs), nt kept on tg only.

constexpr int N     = 1024;
constexpr int NP1   = N + 1;           // 1025
constexpr int PLANE = NP1 * NP1;       // 1050625
constexpr int NN    = N * N;

typedef float floatx4 __attribute__((ext_vector_type(4)));

__device__ __forceinline__ float sigmoidf_fast(float t) {
    return __builtin_amdgcn_rcpf(1.0f + __expf(-t));
}

// 1024 blocks x 256 threads. Each thread owns 4 consecutive interior pixels
// (r, c0..c0+3), c0 % 4 == 0. Threads tid < 8196 additionally handle one
// boundary passthrough cell (disjoint from all main scatter targets).
// Main scatter: planes 0,1 -> (r,c); planes 2,3 -> (r+1,c+1).
__global__ __launch_bounds__(256, 5) void asic_fused(
    const float* __restrict__ x,
    const float* __restrict__ tg,
    const float* __restrict__ rail,
    const int*  __restrict__ mask,
    float* __restrict__ out)
{
    const int tid  = blockIdx.x * 256 + threadIdx.x;   // 262144 threads
    const float g0 = tg[0];

    // ---- boundary passthrough (2n+1 cells per plane, 8196 total) ----
    {
        const int per = 2 * N + 1;  // 2049
        if (tid < 4 * per) {
            const int plane = tid / per;
            const int k = tid % per;
            int r, c;
            if (plane < 2) {                    // row n + col n (rows 0..n-1)
                if (k <= N) { r = N; c = k; }
                else        { r = k - (N + 1); c = N; }
            } else {                            // row 0 + col 0 (rows 1..n)
                if (k <= N) { r = 0; c = k; }
                else        { r = k - N; c = 0; }
            }
            const int flat = plane * PLANE + r * NP1 + c;
            float v = (plane == 3 && c == 0 && r < N) ? x[r] : rail[flat];
            out[flat] = v * (float)mask[flat] * g0;
        }
    }

    // ---- main: 4 pixels per thread ----
    const int pix0 = tid << 2;
    const int r    = pix0 >> 10;
    const int c0   = pix0 & (N - 1);

    // Gather new_inputs (persistent: 16 VGPRs).
    float u[4][4];
    const int b01 = (r + 1) * NP1 + (c0 + 1);
    const int b23 = r * NP1 + c0;
#pragma unroll
    for (int q = 0; q < 4; ++q) {
        u[0][q] = rail[0 * PLANE + b01 + q];
        u[1][q] = rail[1 * PLANE + b01 + q];
        u[2][q] = rail[2 * PLANE + b23 + q];
        u[3][q] = rail[3 * PLANE + b23 + q];
    }
    if (c0 == 0) u[3][0] = x[r];   // view-write of x into plane 3, col 0

#pragma unroll
    for (int i = 0; i < 4; ++i) {
        const int o0 = (i == 0) ? 1 : 0;     // others[i], ascending
        const int o1 = (i <= 1) ? 2 : 1;
        const int o2 = (i <= 2) ? 3 : 2;

        // Issue all 8 gate loads for this phase (independent, stay in flight).
        floatx4 tv[8];
#pragma unroll
        for (int p = 0; p < 8; ++p) {
            tv[p] = __builtin_nontemporal_load(
                reinterpret_cast<const floatx4*>(&tg[(i * 8 + p) * NN + pix0]));
        }

#pragma unroll
        for (int q = 0; q < 4; ++q) {
            // Soft-AND factors for this pixel (recomputed from live u).
            const float a0 = 1.0f - fabsf(u[o0][q]);
            const float a1 = 1.0f - fabsf(1.0f - u[o0][q]);
            const float b0 = 1.0f - fabsf(u[o1][q]);
            const float b1 = 1.0f - fabsf(1.0f - u[o1][q]);
            const float cc0 = 1.0f - fabsf(u[o2][q]);
            const float cc1 = 1.0f - fabsf(1.0f - u[o2][q]);

            // s0 = sum_p w_p factorizes exactly over the 8 bit patterns.
            const float s0 = (a0 + a1) * (b0 + b1) * (cc0 + cc1);

            // s1 = sum_p tw_p w_p, nested contraction over (b2, b1, b0).
            const float tw0 = sigmoidf_fast(tv[0][q]);
            const float tw1 = sigmoidf_fast(tv[1][q]);
            const float tw2 = sigmoidf_fast(tv[2][q]);
            const float tw3 = sigmoidf_fast(tv[3][q]);
            const float tw4 = sigmoidf_fast(tv[4][q]);
            const float tw5 = sigmoidf_fast(tv[5][q]);
            const float tw6 = sigmoidf_fast(tv[6][q]);
            const float tw7 = sigmoidf_fast(tv[7][q]);
            const float d00 = fmaf(tw1, cc1, tw0 * cc0);
            const float d01 = fmaf(tw3, cc1, tw2 * cc0);
            const float d10 = fmaf(tw5, cc1, tw4 * cc0);
            const float d11 = fmaf(tw7, cc1, tw6 * cc0);
            const float e0  = fmaf(b1, d01, b0 * d00);
            const float e1  = fmaf(b1, d11, b0 * d10);
            const float s1  = fmaf(a1, e1, a0 * e0);

            // sum_p toggled_p w_p = (2u-1) s1 + (1-u) s0, clip, mask, scale.
            const float A = 2.0f * u[i][q] - 1.0f;
            const float B = 1.0f - u[i][q];
            float acc = fmaf(A, s1, B * s0);
            acc = fminf(fmaxf(acc, 0.0f), 1.0f);
            const int flat = (i < 2) ? (i * PLANE + r * NP1 + (c0 + q))
                                     : (i * PLANE + (r + 1) * NP1 + (c0 + q + 1));
            out[flat] = acc * (float)mask[flat] * g0;   // plain store: L2 merges
        }
    }
}

extern "C" void kernel_launch(void* const* d_in, const int* in_sizes, int n_in,
                              void* d_out, int out_size, void* d_ws, size_t ws_size,
                              hipStream_t stream) {
    const float* x    = (const float*)d_in[0];   // (n,)
    const float* tg   = (const float*)d_in[1];   // (4,8,n,n)
    const float* rail = (const float*)d_in[2];   // (4*(n+1)^2,)
    const int*   mask = (const int*)d_in[3];     // (4*(n+1)^2,)
    float* out = (float*)d_out;                  // (4*(n+1)^2,) f32

    asic_fused<<<(NN / 4) / 256, 256, 0, stream>>>(x, tg, rail, mask, out);
}